// Round 10
// baseline (304.357 us; speedup 1.0000x reference)
//
#include <hip/hip_runtime.h>
#include <stdint.h>

#define NCLS 172
#define IGN 255
#define HW 65536          // 256*256
#define NPIX 262144       // 4*256*256
#define EPSV 1e-7f
#define NSTAGE 7          // staged partial buffers; 7*520*4 = 14560 B < 16384
#define SS 520            // [0,172) inter | [172,344) cnt | [344,516) union | 516 ce | 517 nvalid
// Workspace layout (EXACTLY the R0-proven 1,064,960 B footprint):
//   [0, 14560)        part (7 stages)
//   [16384, 16384+1MB) sum[NPIX]

// ---------------- Pass A: sequential sumexp sweep ----------------
// grid 1024 = 4 batch x 4 class-groups(43) x 64 spans(1024 px).
// Block stream: 43 runs x 4 KB contiguous (256 thr x float4); sibling blocks
// cover each plane in lockstep -> chip-wide near-sequential read.
// Per-pixel partials combined via global atomicAdd into sum[NPIX].
__global__ __launch_bounds__(256) void seg_sumexp(
    const float* __restrict__ pred, float* __restrict__ sum)
{
    const int bx = blockIdx.x;
    const int sp = bx & 63;            // span of 1024 px
    const int cg = (bx >> 6) & 3;      // class group: 43 classes
    const int b  = bx >> 8;            // batch
    const int tid = threadIdx.x;

    const float4* gp = (const float4*)(pred
        + (size_t)b * NCLS * HW + (size_t)(cg * 43) * HW + sp * 1024) + tid;

    float s0 = 0.f, s1 = 0.f, s2 = 0.f, s3 = 0.f;
    #pragma unroll 8
    for (int k = 0; k < 43; ++k) {
        const float4 x = gp[(size_t)k * (HW / 4)];
        s0 += __expf(x.x); s1 += __expf(x.y);
        s2 += __expf(x.z); s3 += __expf(x.w);
    }
    float* dp = sum + (size_t)b * HW + sp * 1024 + tid * 4;
    atomicAdd(dp + 0, s0); atomicAdd(dp + 1, s1);
    atomicAdd(dp + 2, s2); atomicAdd(dp + 3, s3);
}

// ---------------- Pass B: sequential union + CE sweep ----------------
// grid 1376 = 43 class-quads x 4 batch x 8 spans(8192 px). Per block: four
// interleaved 32 KB sequential pred streams (classes c0..c0+3) + L2-hot
// inv/tgt streams. Union, inter, cnt, nll accumulate in registers; one
// 13-value butterfly + staged global atomics per block.
__global__ __launch_bounds__(256) void seg_union(
    const float* __restrict__ pred, const float* __restrict__ sum,
    const int* __restrict__ tgt, float* __restrict__ part)
{
    const int bx = blockIdx.x;
    const int sp = bx & 7;             // span of 8192 px
    const int b  = (bx >> 3) & 3;      // batch
    const int cq = bx >> 5;            // class quad 0..42
    const int c0 = cq * 4;
    const int tid = threadIdx.x, lane = tid & 63, wv = tid >> 6;

    const size_t pixb = (size_t)b * HW + sp * 8192;
    const float4* iv = (const float4*)(sum + pixb) + tid;
    const int4*   tg = (const int4*)(tgt + pixb) + tid;
    const float*  pb_base = pred + (size_t)b * NCLS * HW + sp * 8192;
    const float4* p0 = (const float4*)(pb_base + (size_t)(c0 + 0) * HW) + tid;
    const float4* p1 = (const float4*)(pb_base + (size_t)(c0 + 1) * HW) + tid;
    const float4* p2 = (const float4*)(pb_base + (size_t)(c0 + 2) * HW) + tid;
    const float4* p3 = (const float4*)(pb_base + (size_t)(c0 + 3) * HW) + tid;

    float u0=0.f,u1=0.f,u2=0.f,u3=0.f;
    float it0=0.f,it1=0.f,it2=0.f,it3=0.f;
    float ct0=0.f,ct1=0.f,ct2=0.f,ct3=0.f;
    float nll=0.f;

    #pragma unroll 2
    for (int j = 0; j < 8; ++j) {
        const int idx = j * 256;
        const float4 sv = iv[idx];
        float4 inv;
        inv.x = 1.f / sv.x; inv.y = 1.f / sv.y;
        inv.z = 1.f / sv.z; inv.w = 1.f / sv.w;
        const int4 t = tg[idx];

        {   const float4 x = p0[idx];
            const float ex=__expf(x.x), ey=__expf(x.y), ez=__expf(x.z), ew=__expf(x.w);
            u0 += ex*inv.x + ey*inv.y + ez*inv.z + ew*inv.w;
            if (t.x == c0) { const float pt=ex*inv.x; it0+=pt; ct0+=1.f; nll-=__logf(pt); }
            if (t.y == c0) { const float pt=ey*inv.y; it0+=pt; ct0+=1.f; nll-=__logf(pt); }
            if (t.z == c0) { const float pt=ez*inv.z; it0+=pt; ct0+=1.f; nll-=__logf(pt); }
            if (t.w == c0) { const float pt=ew*inv.w; it0+=pt; ct0+=1.f; nll-=__logf(pt); }
        }
        {   const float4 x = p1[idx];
            const float ex=__expf(x.x), ey=__expf(x.y), ez=__expf(x.z), ew=__expf(x.w);
            u1 += ex*inv.x + ey*inv.y + ez*inv.z + ew*inv.w;
            if (t.x == c0+1) { const float pt=ex*inv.x; it1+=pt; ct1+=1.f; nll-=__logf(pt); }
            if (t.y == c0+1) { const float pt=ey*inv.y; it1+=pt; ct1+=1.f; nll-=__logf(pt); }
            if (t.z == c0+1) { const float pt=ez*inv.z; it1+=pt; ct1+=1.f; nll-=__logf(pt); }
            if (t.w == c0+1) { const float pt=ew*inv.w; it1+=pt; ct1+=1.f; nll-=__logf(pt); }
        }
        {   const float4 x = p2[idx];
            const float ex=__expf(x.x), ey=__expf(x.y), ez=__expf(x.z), ew=__expf(x.w);
            u2 += ex*inv.x + ey*inv.y + ez*inv.z + ew*inv.w;
            if (t.x == c0+2) { const float pt=ex*inv.x; it2+=pt; ct2+=1.f; nll-=__logf(pt); }
            if (t.y == c0+2) { const float pt=ey*inv.y; it2+=pt; ct2+=1.f; nll-=__logf(pt); }
            if (t.z == c0+2) { const float pt=ez*inv.z; it2+=pt; ct2+=1.f; nll-=__logf(pt); }
            if (t.w == c0+2) { const float pt=ew*inv.w; it2+=pt; ct2+=1.f; nll-=__logf(pt); }
        }
        {   const float4 x = p3[idx];
            const float ex=__expf(x.x), ey=__expf(x.y), ez=__expf(x.z), ew=__expf(x.w);
            u3 += ex*inv.x + ey*inv.y + ez*inv.z + ew*inv.w;
            if (t.x == c0+3) { const float pt=ex*inv.x; it3+=pt; ct3+=1.f; nll-=__logf(pt); }
            if (t.y == c0+3) { const float pt=ey*inv.y; it3+=pt; ct3+=1.f; nll-=__logf(pt); }
            if (t.z == c0+3) { const float pt=ez*inv.z; it3+=pt; ct3+=1.f; nll-=__logf(pt); }
            if (t.w == c0+3) { const float pt=ew*inv.w; it3+=pt; ct3+=1.f; nll-=__logf(pt); }
        }
    }

    // ---- reduce 13 block-level values: butterfly + cross-wave LDS ----
    float vals[13] = {u0,u1,u2,u3, it0,it1,it2,it3, ct0,ct1,ct2,ct3, nll};
    #pragma unroll
    for (int i = 0; i < 13; ++i) {
        float v = vals[i];
        #pragma unroll
        for (int m = 32; m > 0; m >>= 1) v += __shfl_xor(v, m, 64);
        vals[i] = v;
    }
    __shared__ float red[4][13];
    if (lane == 0) {
        #pragma unroll
        for (int i = 0; i < 13; ++i) red[wv][i] = vals[i];
    }
    __syncthreads();

    float* pb = part + (size_t)(bx % NSTAGE) * SS;
    if (tid < 13) {
        const float v = red[0][tid] + red[1][tid] + red[2][tid] + red[3][tid];
        if (tid < 4)       atomicAdd(&pb[344 + c0 + tid], v);
        else if (tid < 8)  { if (v != 0.f) atomicAdd(&pb[c0 + tid - 4], v); }
        else if (tid < 12) { if (v != 0.f) atomicAdd(&pb[172 + c0 + tid - 8], v); }
        else               { if (v != 0.f) atomicAdd(&pb[516], v); }
    }
    if (tid == 13) {
        float cs = 0.f;
        #pragma unroll
        for (int w = 0; w < 4; ++w)
            cs += red[w][8] + red[w][9] + red[w][10] + red[w][11];
        if (cs != 0.f) atomicAdd(&pb[517], cs);
    }
}

__global__ __launch_bounds__(256) void seg_fin(
    const float* __restrict__ part, float* __restrict__ out)
{
    __shared__ float sT[256], sN[256];
    const int tid = threadIdx.x;
    float term = 0.f, nv = 0.f;
    if (tid < NCLS) {
        float inter = 0.f, cnt = 0.f, uni = 0.f;
        for (int st = 0; st < NSTAGE; ++st) {
            inter += part[st * SS + tid];
            cnt   += part[st * SS + NCLS + tid];
            uni   += part[st * SS + 344 + tid];
        }
        const float u = uni + cnt;
        if (u > 0.f) { term = (2.f * inter + EPSV) / (u + EPSV); nv = 1.f; }
    }
    sT[tid] = term; sN[tid] = nv;
    __syncthreads();
    #pragma unroll
    for (int s2 = 128; s2 > 0; s2 >>= 1) {
        if (tid < s2) { sT[tid] += sT[tid + s2]; sN[tid] += sN[tid + s2]; }
        __syncthreads();
    }
    if (tid == 0) {
        float ce = 0.f, nvl = 0.f;
        for (int st = 0; st < NSTAGE; ++st) {
            ce  += part[st * SS + 516];
            nvl += part[st * SS + 517];
        }
        const float ceo  = ce / fmaxf(nvl, 1.f);
        const float dice = (sN[0] > 0.f) ? (1.f - sT[0] / fmaxf(sN[0], 1.f)) : 0.f;
        out[0] = ceo + 0.5f * dice;
    }
}

extern "C" void kernel_launch(void* const* d_in, const int* in_sizes, int n_in,
                              void* d_out, int out_size, void* d_ws, size_t ws_size,
                              hipStream_t stream) {
    const float* pred = (const float*)d_in[0];
    const int*   tgt  = (const int*)d_in[1];
    float* out  = (float*)d_out;

    char* ws = (char*)d_ws;
    float* part = (float*)ws;                       // 7*520*4 = 14560 B
    float* sum  = (float*)(ws + 16384);             // NPIX floats = 1 MB

    hipMemsetAsync(d_ws, 0, 16384 + NPIX * 4, stream);   // 1,064,960 B total
    seg_sumexp<<<1024, 256, 0, stream>>>(pred, sum);
    seg_union<<<1376, 256, 0, stream>>>(pred, sum, tgt, part);
    seg_fin<<<1, 256, 0, stream>>>(part, out);
}